// Round 4
// baseline (135.256 us; speedup 1.0000x reference)
//
#include <hip/hip_runtime.h>

#define B 32
#define T 65536
#define EPSF 1e-7f
#define TPB 256
#define CHUNK 512
#define NCHUNKB (T / CHUNK)      // 128 chunks per b
#define NBLK (B * NCHUNKB)       // 4096 blocks
#define NACC 21                  // 16 term1 + 4 term2 + 1 vad
// ws layout: part[B][NACC][NCHUNKB] floats = 32*21*128 = 86016 floats (344 KB)

__device__ __forceinline__ float wave_reduce_sum(float v) {
    #pragma unroll
    for (int off = 32; off > 0; off >>= 1) v += __shfl_down(v, off, 64);
    return v;
}

__device__ __forceinline__ void accum_t(float4 p4, float4 l4, float pvv, float vdd,
                                        float (&a1)[16], float (&a2)[4], float& av) {
    const float p[4] = {p4.x, p4.y, p4.z, p4.w};
    const float l[4] = {l4.x, l4.y, l4.z, l4.w};
    float d[4];
    #pragma unroll
    for (int i = 0; i < 4; ++i) {
        const float pc = fminf(fmaxf(p[i], EPSF), 1.0f - EPSF);
        const float lp = __logf(pc);
        const float lq = __logf(1.0f - pc);
        a2[i] += lq;
        d[i] = lp - lq;
    }
    #pragma unroll
    for (int i = 0; i < 4; ++i)
        #pragma unroll
        for (int j = 0; j < 4; ++j)
            a1[i * 4 + j] = fmaf(d[i], l[j], a1[i * 4 + j]);
    const float pvc = fminf(fmaxf(pvv, EPSF), 1.0f - EPSF);
    av += __logf((vdd > 0.5f) ? pvc : (1.0f - pvc));  // vad is exactly 0/1
}

__global__ __launch_bounds__(TPB) void main_kernel(
    const float4* __restrict__ ps,   // pred_speakers [B,T,4]
    const float*  __restrict__ pv,   // pred_vad [B,T]
    const float4* __restrict__ lb,   // labels [B,T,4]
    const float*  __restrict__ vd,   // vad [B,T]
    const int*    __restrict__ len,  // lengths [B] int32
    float* __restrict__ part)        // [B][NACC][NCHUNKB]
{
    const int b  = blockIdx.x >> 7;      // / NCHUNKB
    const int c  = blockIdx.x & (NCHUNKB - 1);
    const int t0 = c * CHUNK;
    const int L  = len[b];
    const int tid = threadIdx.x;

    float a1[16], a2[4], av = 0.0f;
    #pragma unroll
    for (int k = 0; k < 16; ++k) a1[k] = 0.0f;
    #pragma unroll
    for (int k = 0; k < 4; ++k)  a2[k] = 0.0f;

    if (t0 < L) {                        // block-uniform prefix mask
        const int base = b * T;
        if (t0 + CHUNK <= L) {
            // fast path: whole chunk active; issue all 8 loads up front for MLP
            const int ta = base + t0 + tid;
            const int tb2 = ta + TPB;
            const float4 P0 = ps[ta],  P1 = ps[tb2];
            const float4 L0 = lb[ta],  L1 = lb[tb2];
            const float  v0 = pv[ta],  v1 = pv[tb2];
            const float  w0 = vd[ta],  w1 = vd[tb2];
            accum_t(P0, L0, v0, w0, a1, a2, av);
            accum_t(P1, L1, v1, w1, a1, a2, av);
        } else {
            // boundary chunk: per-lane predicate
            #pragma unroll
            for (int u = 0; u < 2; ++u) {
                const int t = t0 + tid + u * TPB;
                if (t < L) {
                    const int g = b * T + t;
                    accum_t(ps[g], lb[g], pv[g], vd[g], a1, a2, av);
                }
            }
        }
    }

    // block-reduce 21 partials, then one non-atomic store per cell
    __shared__ float smem[TPB / 64][NACC];
    const int lane = tid & 63;
    const int wv   = tid >> 6;

    float vals[NACC];
    #pragma unroll
    for (int k = 0; k < 16; ++k) vals[k] = a1[k];
    #pragma unroll
    for (int k = 0; k < 4; ++k)  vals[16 + k] = a2[k];
    vals[20] = av;

    #pragma unroll
    for (int k = 0; k < NACC; ++k) {
        const float r = wave_reduce_sum(vals[k]);
        if (lane == 0) smem[wv][k] = r;
    }
    __syncthreads();
    if (tid < NACC) {
        float s = 0.0f;
        #pragma unroll
        for (int w = 0; w < TPB / 64; ++w) s += smem[w][tid];
        part[(b * NACC + tid) * NCHUNKB + c] = s;   // unconditional write, no init needed
    }
}

__global__ __launch_bounds__(704) void final_kernel(
    const float* __restrict__ part,
    const int*   __restrict__ len,
    float* __restrict__ out)
{
    __shared__ float sums[B][NACC];
    const int tid = threadIdx.x;

    if (tid < B * NACC) {
        const float4* p4 = (const float4*)(part + (size_t)tid * NCHUNKB);
        float4 a = {0.f, 0.f, 0.f, 0.f};
        #pragma unroll
        for (int i = 0; i < NCHUNKB / 4; ++i) {
            const float4 v = p4[i];
            a.x += v.x; a.y += v.y; a.z += v.z; a.w += v.w;
        }
        sums[tid / NACC][tid % NACC] = (a.x + a.y) + (a.z + a.w);
    }
    __syncthreads();

    if (tid < 64) {
        float best = 0.0f, vadn = 0.0f, lensum = 0.0f;
        if (tid < B) {
            const int bb = tid;
            const float msum = (float)len[bb];
            float Lm[16];
            #pragma unroll
            for (int i = 0; i < 4; ++i)
                #pragma unroll
                for (int j = 0; j < 4; ++j)
                    Lm[i * 4 + j] = (-sums[bb][i * 4 + j] - sums[bb][16 + i]) / msum;

            best = 1e30f;
            #pragma unroll
            for (int p0 = 0; p0 < 4; ++p0)
                #pragma unroll
                for (int p1 = 0; p1 < 4; ++p1) {
                    if (p1 == p0) continue;
                    #pragma unroll
                    for (int p2 = 0; p2 < 4; ++p2) {
                        if (p2 == p0 || p2 == p1) continue;
                        const int p3 = 6 - p0 - p1 - p2;
                        best = fminf(best, Lm[p0] + Lm[4 + p1] + Lm[8 + p2] + Lm[12 + p3]);
                    }
                }
            best *= 0.25f;                 // mean over S
            vadn   = -sums[bb][20];        // masked VAD BCE numerator
            lensum = msum;
        }
        best   = wave_reduce_sum(best);
        vadn   = wave_reduce_sum(vadn);
        lensum = wave_reduce_sum(lensum);
        if (tid == 0)
            out[0] = best * (1.0f / B) + 0.5f * (vadn / lensum);
    }
}

extern "C" void kernel_launch(void* const* d_in, const int* in_sizes, int n_in,
                              void* d_out, int out_size, void* d_ws, size_t ws_size,
                              hipStream_t stream) {
    const float4* ps  = (const float4*)d_in[0];
    const float*  pv  = (const float*)d_in[1];
    const float4* lb  = (const float4*)d_in[2];
    const float*  vd  = (const float*)d_in[3];
    const int*    len = (const int*)d_in[4];
    float*        part = (float*)d_ws;     // B*NACC*NCHUNKB floats
    float*        out  = (float*)d_out;

    main_kernel<<<NBLK, TPB, 0, stream>>>(ps, pv, lb, vd, len, part);
    final_kernel<<<1, 704, 0, stream>>>(part, len, out);
}

// Round 5
// 116.263 us; speedup vs baseline: 1.1634x; 1.1634x over previous
//
#include <hip/hip_runtime.h>

#define B 32
#define T 65536
#define EPSF 1e-7f
#define TPB 256
#define CHUNK 1024               // 4 t per thread
#define NCHUNKB (T / CHUNK)      // 64 chunks per b
#define NBLK (B * NCHUNKB)       // 2048 blocks
#define NACC 21                  // 16 term1 + 4 term2 + 1 vad
#define NCOL (B * NACC)          // 672
// ws layout: part[NCHUNKB][B*NACC] floats = 64*672 = 43008 floats (172 KB)

__device__ __forceinline__ float wave_reduce_sum(float v) {
    #pragma unroll
    for (int off = 32; off > 0; off >>= 1) v += __shfl_down(v, off, 64);
    return v;
}

__device__ __forceinline__ void accum_t(float4 p4, float4 l4, float pvv, float vdd,
                                        float (&a1)[16], float (&a2)[4], float& av) {
    const float p[4] = {p4.x, p4.y, p4.z, p4.w};
    const float l[4] = {l4.x, l4.y, l4.z, l4.w};
    float d[4];
    #pragma unroll
    for (int i = 0; i < 4; ++i) {
        const float pc = fminf(fmaxf(p[i], EPSF), 1.0f - EPSF);
        const float lp = __logf(pc);
        const float lq = __logf(1.0f - pc);
        a2[i] += lq;
        d[i] = lp - lq;
    }
    #pragma unroll
    for (int i = 0; i < 4; ++i)
        #pragma unroll
        for (int j = 0; j < 4; ++j)
            a1[i * 4 + j] = fmaf(d[i], l[j], a1[i * 4 + j]);
    const float pvc = fminf(fmaxf(pvv, EPSF), 1.0f - EPSF);
    av += __logf((vdd > 0.5f) ? pvc : (1.0f - pvc));  // vad is exactly 0/1
}

__global__ __launch_bounds__(TPB) void partial_kernel(
    const float4* __restrict__ ps,   // pred_speakers [B,T,4]
    const float*  __restrict__ pv,   // pred_vad [B,T]
    const float4* __restrict__ lb,   // labels [B,T,4]
    const float*  __restrict__ vd,   // vad [B,T]
    const int*    __restrict__ len,  // lengths [B] int32
    float* __restrict__ part)        // [NCHUNKB][B*NACC]
{
    const int b  = blockIdx.x >> 6;          // / NCHUNKB
    const int c  = blockIdx.x & (NCHUNKB - 1);
    const int t0 = c * CHUNK;
    const int L  = len[b];
    const int tid = threadIdx.x;

    float a1[16], a2[4], av = 0.0f;
    #pragma unroll
    for (int k = 0; k < 16; ++k) a1[k] = 0.0f;
    #pragma unroll
    for (int k = 0; k < 4; ++k)  a2[k] = 0.0f;

    if (t0 < L) {                            // block-uniform prefix mask
        const int base = b * T + t0 + tid;
        if (t0 + CHUNK <= L) {
            // fast path: hoist ALL loads (16 load-insts in flight) then compute
            float4 P[4], Q[4];
            float  V[4], W[4];
            #pragma unroll
            for (int u = 0; u < 4; ++u) {
                const int g = base + u * TPB;
                P[u] = ps[g];  Q[u] = lb[g];  V[u] = pv[g];  W[u] = vd[g];
            }
            #pragma unroll
            for (int u = 0; u < 4; ++u)
                accum_t(P[u], Q[u], V[u], W[u], a1, a2, av);
        } else {
            // boundary chunk: per-lane predicate
            #pragma unroll
            for (int u = 0; u < 4; ++u) {
                const int t = t0 + tid + u * TPB;
                if (t < L) {
                    const int g = b * T + t;
                    accum_t(ps[g], lb[g], pv[g], vd[g], a1, a2, av);
                }
            }
        }
    }

    // block-reduce 21 partials, then one plain store per cell (no init, no atomics)
    __shared__ float smem[TPB / 64][NACC];
    const int lane = tid & 63;
    const int wv   = tid >> 6;

    float vals[NACC];
    #pragma unroll
    for (int k = 0; k < 16; ++k) vals[k] = a1[k];
    #pragma unroll
    for (int k = 0; k < 4; ++k)  vals[16 + k] = a2[k];
    vals[20] = av;

    #pragma unroll
    for (int k = 0; k < NACC; ++k) {
        const float r = wave_reduce_sum(vals[k]);
        if (lane == 0) smem[wv][k] = r;
    }
    __syncthreads();
    if (tid < NACC) {
        float s = 0.0f;
        #pragma unroll
        for (int w = 0; w < TPB / 64; ++w) s += smem[w][tid];
        part[c * NCOL + b * NACC + tid] = s;   // unconditional write
    }
}

__global__ __launch_bounds__(704) void final_kernel(
    const float* __restrict__ part,   // [NCHUNKB][B*NACC]
    const int*   __restrict__ len,
    float* __restrict__ out)
{
    __shared__ float sums[B][NACC];
    const int tid = threadIdx.x;

    if (tid < NCOL) {
        // coalesced: consecutive tid -> consecutive addresses; 64 strided rows
        float a = 0.0f;
        #pragma unroll
        for (int c = 0; c < NCHUNKB; ++c)
            a += part[c * NCOL + tid];
        sums[tid / NACC][tid % NACC] = a;
    }
    __syncthreads();

    if (tid < 64) {
        float best = 0.0f, vadn = 0.0f, lensum = 0.0f;
        if (tid < B) {
            const int bb = tid;
            const float msum = (float)len[bb];
            float Lm[16];
            #pragma unroll
            for (int i = 0; i < 4; ++i)
                #pragma unroll
                for (int j = 0; j < 4; ++j)
                    Lm[i * 4 + j] = (-sums[bb][i * 4 + j] - sums[bb][16 + i]) / msum;

            best = 1e30f;
            #pragma unroll
            for (int p0 = 0; p0 < 4; ++p0)
                #pragma unroll
                for (int p1 = 0; p1 < 4; ++p1) {
                    if (p1 == p0) continue;
                    #pragma unroll
                    for (int p2 = 0; p2 < 4; ++p2) {
                        if (p2 == p0 || p2 == p1) continue;
                        const int p3 = 6 - p0 - p1 - p2;
                        best = fminf(best, Lm[p0] + Lm[4 + p1] + Lm[8 + p2] + Lm[12 + p3]);
                    }
                }
            best *= 0.25f;                 // mean over S
            vadn   = -sums[bb][20];        // masked VAD BCE numerator
            lensum = msum;
        }
        best   = wave_reduce_sum(best);
        vadn   = wave_reduce_sum(vadn);
        lensum = wave_reduce_sum(lensum);
        if (tid == 0)
            out[0] = best * (1.0f / B) + 0.5f * (vadn / lensum);
    }
}

extern "C" void kernel_launch(void* const* d_in, const int* in_sizes, int n_in,
                              void* d_out, int out_size, void* d_ws, size_t ws_size,
                              hipStream_t stream) {
    const float4* ps  = (const float4*)d_in[0];
    const float*  pv  = (const float*)d_in[1];
    const float4* lb  = (const float4*)d_in[2];
    const float*  vd  = (const float*)d_in[3];
    const int*    len = (const int*)d_in[4];
    float*        part = (float*)d_ws;     // NCHUNKB*B*NACC floats
    float*        out  = (float*)d_out;

    partial_kernel<<<NBLK, TPB, 0, stream>>>(ps, pv, lb, vd, len, part);
    final_kernel<<<1, 704, 0, stream>>>(part, len, out);
}